// Round 16
// baseline (241.742 us; speedup 1.0000x reference)
//
#include <hip/hip_runtime.h>

// ---------------------------------------------------------------------------
// GCN link prediction forward on MI355X.  R16 = R15 with the row-sort fused
// into scatter_ell's tail (rows are XCD-L2-hot right after the block writes
// them: ~6us marginal vs 18.7us standalone) and the qcur memset folded into
// prep. Pipeline (7 launches):
//  1) prep: blocks 0..63 W1->wfrag; block 64: wu,wv,cvals + qcur=0
//  2) bucket_edges: queues[d>>10] += pack(src, d&1023)  (1 read of edges)
//  3) scatter_ell: LDS-atomic ELL fill -> cnt+dinv -> in-place bitonic sort
//     of each row (ascending, INT_MAX pad) while rows are L2-hot
//  4) gemm1_mfma: h1b = bf16((emb[x] @ W1) * dinv)   [N][128] bf16
//  5) agg1_ln: 4-deep 16B/lane gather + in-reg LN -> tuv = (tu,tv) 8B/node
//  6) agg2: Su/Sv scalar aggregation over sorted rows
//  7) decode: out = Su[a]+Sv[b]+c0
// Determinism: sorted rows are a function of the edge multiset only, so all
// fp32 sum orders are reproducible across replays.
// agg1 is at the 8-XCD L2-replication floor (~190MB fetch @ ~2.9TB/s);
// R10 (depth), R11 (sorted locality), R7 (dim-split), R8 (fusion) all
// confirmed no structural lever remains there.
// ---------------------------------------------------------------------------

typedef __attribute__((ext_vector_type(8))) __bf16 bf16x8;
typedef __attribute__((ext_vector_type(4))) __bf16 bf16x4;
typedef __attribute__((ext_vector_type(4))) float f32x4;

static __device__ __forceinline__ float bfl(unsigned u) { return __uint_as_float(u << 16); }
static __device__ __forceinline__ float bfh(unsigned u) { return __uint_as_float(u & 0xFFFF0000u); }

// 64-lane bitonic sort (ascending). Uniform, 21 shfl_xor stages.
static __device__ __forceinline__ int bitonic64(int key, int lane) {
#pragma unroll
  for (int k = 2; k <= 64; k <<= 1) {
#pragma unroll
    for (int j = k >> 1; j > 0; j >>= 1) {
      int partner = __shfl_xor(key, j, 64);
      bool up = (lane & k) != 0;      // descending half of the k-block
      bool lower = (lane & j) == 0;   // lower lane of the pair
      int mn = min(key, partner), mx = max(key, partner);
      key = (lower ^ up) ? mn : mx;
    }
  }
  return key;
}

// blocks 0..63: W1 fragment table. block 64: linear-collapse constants + qcur=0.
__global__ __launch_bounds__(256) void prep(const float* __restrict__ W1,
                                            const float* __restrict__ W2,
                                            const float* __restrict__ b2,
                                            const float* __restrict__ L1,
                                            const float* __restrict__ L2,
                                            const float* __restrict__ bl1,
                                            const float* __restrict__ bl2,
                                            ushort* __restrict__ wfrag,
                                            float* __restrict__ wu,
                                            float* __restrict__ wv,
                                            float* __restrict__ cvals,
                                            int* __restrict__ qcur) {
  int t = threadIdx.x;
  if (blockIdx.x < 64) {
    int idx = blockIdx.x * 256 + t;  // 16384 elements
    int j = idx & 7, lane = (idx >> 3) & 63, ct = (idx >> 9) & 7, kt = idx >> 12;
    int k = kt * 32 + (lane >> 4) * 8 + j;
    int col = ct * 16 + (lane & 15);
    __bf16 h = (__bf16)W1[k * 128 + col];
    wfrag[idx] = __builtin_bit_cast(ushort, h);
    return;
  }
#pragma unroll
  for (int i = t; i < 1024; i += 256) qcur[i] = 0;
  __shared__ float us[32];  // w = L1@L2
  if (t < 32) {
    float a = 0.f;
    for (int j = 0; j < 16; ++j) a += L1[t * 16 + j] * L2[j];
    us[t] = a;
  }
  __syncthreads();
  if (t < 128) {
    float a = 0.f, b = 0.f;
    for (int k = 0; k < 16; ++k) {
      float w = W2[t * 16 + k];
      a += w * us[k];
      b += w * us[16 + k];
    }
    wu[t] = a;
    wv[t] = b;
  } else if (t == 128) {
    float a = 0.f;
    for (int k = 0; k < 16; ++k) a += b2[k] * us[k];
    cvals[0] = a;  // cu
  } else if (t == 129) {
    float a = 0.f;
    for (int k = 0; k < 16; ++k) a += b2[k] * us[16 + k];
    cvals[1] = a;  // cv
  } else if (t == 130) {
    float a = 0.f;
    for (int j = 0; j < 16; ++j) a += bl1[j] * L2[j];
    cvals[2] = a + bl2[0];  // c0
  }
}

// Pass 1: read edges once, route to NB per-slice queues (slice = 1024 dsts).
// Entry = src | (localdst << 22).
__global__ __launch_bounds__(256) void bucket_edges(const int* __restrict__ src,
                                                    const int* __restrict__ dst,
                                                    int E, int NB,
                                                    int* __restrict__ qcur,
                                                    unsigned* __restrict__ queues,
                                                    int qcap) {
  __shared__ int lcnt[128];
  __shared__ int lbase[128];
  int t = threadIdx.x;
  int CH = (E + gridDim.x - 1) / gridDim.x;
  int beg = blockIdx.x * CH;
  int end = min(E, beg + CH);
  for (int i = t; i < NB; i += 256) lcnt[i] = 0;
  __syncthreads();
  for (int e = beg + t; e < end; e += 256) atomicAdd(&lcnt[dst[e] >> 10], 1);
  __syncthreads();
  for (int i = t; i < NB; i += 256) {
    lbase[i] = atomicAdd(&qcur[i], lcnt[i]);
    lcnt[i] = 0;
  }
  __syncthreads();
  for (int e = beg + t; e < end; e += 256) {  // chunk is L2-hot now
    int d = dst[e];
    int p = d >> 10;
    int pos = lbase[p] + atomicAdd(&lcnt[p], 1);
    if (pos < qcap)
      queues[(size_t)p * qcap + pos] =
          (unsigned)src[e] | ((unsigned)(d - (p << 10)) << 22);
  }
}

// Pass 2: one block per slice. LDS-atomic ELL fill, emit cnt+dinv, then sort
// each row in place (rows are resident in this XCD's L2 — just written).
__global__ __launch_bounds__(1024) void scatter_ell(const unsigned* __restrict__ queues,
                                                    const int* __restrict__ qcur,
                                                    int qcap, int* __restrict__ cnt,
                                                    float* __restrict__ dinv,
                                                    int* __restrict__ colsrc, int N) {
  __shared__ int lcnt[1024];
  int b = blockIdx.x, t = threadIdx.x;
  lcnt[t] = 0;
  __syncthreads();
  int len = min(qcur[b], qcap);
  const unsigned* q = queues + (size_t)b * qcap;
  int lo = b << 10;
  for (int i = t; i < len; i += 1024) {
    unsigned u = q[i];
    unsigned ld = u >> 22;
    int pos = atomicAdd(&lcnt[ld], 1);
    if (pos < 64) colsrc[(size_t)(lo + ld) * 64 + pos] = (int)(u & 0x3FFFFFu);
  }
  __syncthreads();
  if (lo + t < N) {
    int c = min(lcnt[t], 64);
    cnt[lo + t] = c;
    dinv[lo + t] = rsqrtf((float)(c + 1));
  }
  __syncthreads();  // colsrc writes by this block now visible block-wide
  int wave = t >> 6, lane = t & 63;
  for (int r = wave * 64; r < wave * 64 + 64; ++r) {  // 16 waves x 64 rows
    int nd = lo + r;
    if (nd >= N) break;
    int cr = min(lcnt[r], 64);
    int* row = colsrc + (size_t)nd * 64;
    int key = (lane < cr) ? row[lane] : 0x7FFFFFFF;
    key = bitonic64(key, lane);
    row[lane] = key;
  }
}

// h1b[node][dim] bf16 = (emb[x[node]] @ W1) * dinv[node], via 16x16x32 MFMA.
__global__ __launch_bounds__(256) void gemm1_mfma(
    const int* __restrict__ x, const float* __restrict__ emb,
    const ushort* __restrict__ wfrag, const float* __restrict__ dinv,
    unsigned* __restrict__ h1b, int N) {
  __shared__ alignas(16) ushort Wlds[16384];  // 32 KB frag table
  int t = threadIdx.x;
  for (int i = t; i < 2048; i += 256)
    ((uint4*)Wlds)[i] = ((const uint4*)wfrag)[i];
  __syncthreads();
  int w = t >> 6, lane = t & 63;
  int row0 = blockIdx.x * 128 + w * 32;  // this wave: nodes row0..row0+31
  int rB = lane & 15, kg = lane >> 4;
  int n0 = row0 + rB, n1 = row0 + 16 + rB;
  const float* e0 = emb + (size_t)x[min(n0, N - 1)] * 128 + kg * 8;
  const float* e1 = emb + (size_t)x[min(n1, N - 1)] * 128 + kg * 8;
  f32x4 acc[2][8];
#pragma unroll
  for (int g = 0; g < 2; ++g)
#pragma unroll
    for (int ct = 0; ct < 8; ++ct) acc[g][ct] = (f32x4)(0.f);
#pragma unroll
  for (int kt = 0; kt < 4; ++kt) {
    float4 p0 = *(const float4*)(e0 + kt * 32);
    float4 p1 = *(const float4*)(e0 + kt * 32 + 4);
    float4 q0 = *(const float4*)(e1 + kt * 32);
    float4 q1 = *(const float4*)(e1 + kt * 32 + 4);
    bf16x8 fb0, fb1;
    fb0[0] = (__bf16)p0.x; fb0[1] = (__bf16)p0.y; fb0[2] = (__bf16)p0.z; fb0[3] = (__bf16)p0.w;
    fb0[4] = (__bf16)p1.x; fb0[5] = (__bf16)p1.y; fb0[6] = (__bf16)p1.z; fb0[7] = (__bf16)p1.w;
    fb1[0] = (__bf16)q0.x; fb1[1] = (__bf16)q0.y; fb1[2] = (__bf16)q0.z; fb1[3] = (__bf16)q0.w;
    fb1[4] = (__bf16)q1.x; fb1[5] = (__bf16)q1.y; fb1[6] = (__bf16)q1.z; fb1[7] = (__bf16)q1.w;
#pragma unroll
    for (int ct = 0; ct < 8; ++ct) {
      bf16x8 wv = *(const bf16x8*)&Wlds[((kt * 8 + ct) * 64 + lane) * 8];
      acc[0][ct] = __builtin_amdgcn_mfma_f32_16x16x32_bf16(wv, fb0, acc[0][ct], 0, 0, 0);
      acc[1][ct] = __builtin_amdgcn_mfma_f32_16x16x32_bf16(wv, fb1, acc[1][ct], 0, 0, 0);
    }
  }
#pragma unroll
  for (int g = 0; g < 2; ++g) {
    int node = row0 + g * 16 + rB;
    if (node < N) {
      float dv = dinv[node];
#pragma unroll
      for (int ct = 0; ct < 8; ++ct) {
        f32x4 a = acc[g][ct];
        bf16x4 o;
        o[0] = (__bf16)(a[0] * dv); o[1] = (__bf16)(a[1] * dv);
        o[2] = (__bf16)(a[2] * dv); o[3] = (__bf16)(a[3] * dv);
        *(uint2*)&h1b[(size_t)node * 64 + ct * 8 + kg * 2] = __builtin_bit_cast(uint2, o);
      }
    }
  }
}

// wave/node: lane=(g,dq) g in [0,4), dq in [0,16); 16B/lane, 4-deep gather
// pipeline over the pre-sorted row. Epilogue: LN in fp32 regs, tu/tv dots
// vs wu/wv, write tuv (8B/node).
__global__ __launch_bounds__(256) void agg1_ln(const unsigned* __restrict__ h1b,
                                               const int* __restrict__ cnt_a,
                                               const int* __restrict__ colsrc,
                                               const float* __restrict__ dinv,
                                               const float* __restrict__ b1,
                                               const float* __restrict__ lng,
                                               const float* __restrict__ lnb,
                                               const float* __restrict__ wu,
                                               const float* __restrict__ wv,
                                               float2* __restrict__ tuv, int N) {
  int v = blockIdx.x * 4 + (threadIdx.x >> 6);
  int lane = threadIdx.x & 63;
  if (v >= N) return;
  int g = lane >> 4, dq = lane & 15;
  const uint4* tb = (const uint4*)h1b;  // row = 16 x uint4
  int cnt = cnt_a[v];
  int myidx = (lane < cnt) ? colsrc[(size_t)v * 64 + lane] : 0;
  float a0 = 0.f, a1 = 0.f, a2 = 0.f, a3 = 0.f;
  float a4 = 0.f, a5 = 0.f, a6 = 0.f, a7 = 0.f;
#define ACC1(m)                                              \
  {                                                          \
    a0 += bfl(m.x); a1 += bfh(m.x); a2 += bfl(m.y);          \
    a3 += bfh(m.y); a4 += bfl(m.z); a5 += bfh(m.z);          \
    a6 += bfl(m.w); a7 += bfh(m.w);                          \
  }
  if (g == 0) {  // self loop (pre-scaled)
    uint4 ms = tb[(size_t)v * 16 + dq];
    ACC1(ms);
  }
  int i = 0;
  for (; i + 16 <= cnt; i += 16) {  // 16 rows in flight across the wave
    int s0 = __shfl(myidx, i + g, 64);
    int s1_ = __shfl(myidx, i + 4 + g, 64);
    int s2_ = __shfl(myidx, i + 8 + g, 64);
    int s3_ = __shfl(myidx, i + 12 + g, 64);
    uint4 m0 = tb[(size_t)s0 * 16 + dq];
    uint4 m1 = tb[(size_t)s1_ * 16 + dq];
    uint4 m2 = tb[(size_t)s2_ * 16 + dq];
    uint4 m3 = tb[(size_t)s3_ * 16 + dq];
    ACC1(m0);
    ACC1(m1);
    ACC1(m2);
    ACC1(m3);
  }
  {  // tail: 4 predicated steps cover all <=15 remaining slots
    int slot0 = i + g, slot1 = i + 4 + g, slot2 = i + 8 + g, slot3 = i + 12 + g;
    int c1 = max(cnt - 1, 0);
    int t0 = __shfl(myidx, min(slot0, c1), 64);
    int t1 = __shfl(myidx, min(slot1, c1), 64);
    int t2 = __shfl(myidx, min(slot2, c1), 64);
    int t3 = __shfl(myidx, min(slot3, c1), 64);
    if (slot0 < cnt) { uint4 m = tb[(size_t)t0 * 16 + dq]; ACC1(m); }
    if (slot1 < cnt) { uint4 m = tb[(size_t)t1 * 16 + dq]; ACC1(m); }
    if (slot2 < cnt) { uint4 m = tb[(size_t)t2 * 16 + dq]; ACC1(m); }
    if (slot3 < cnt) { uint4 m = tb[(size_t)t3 * 16 + dq]; ACC1(m); }
  }
#undef ACC1
#pragma unroll
  for (int off = 16; off < 64; off <<= 1) {  // cross-group reduce
    a0 += __shfl_xor(a0, off, 64);
    a1 += __shfl_xor(a1, off, 64);
    a2 += __shfl_xor(a2, off, 64);
    a3 += __shfl_xor(a3, off, 64);
    a4 += __shfl_xor(a4, off, 64);
    a5 += __shfl_xor(a5, off, 64);
    a6 += __shfl_xor(a6, off, 64);
    a7 += __shfl_xor(a7, off, 64);
  }
  float dv = dinv[v];
  float4 bb0 = ((const float4*)b1)[dq * 2];
  float4 bb1 = ((const float4*)b1)[dq * 2 + 1];
  float v0 = fmaxf(a0 * dv + bb0.x, 0.f);
  float v1 = fmaxf(a1 * dv + bb0.y, 0.f);
  float v2 = fmaxf(a2 * dv + bb0.z, 0.f);
  float v3 = fmaxf(a3 * dv + bb0.w, 0.f);
  float v4 = fmaxf(a4 * dv + bb1.x, 0.f);
  float v5 = fmaxf(a5 * dv + bb1.y, 0.f);
  float v6 = fmaxf(a6 * dv + bb1.z, 0.f);
  float v7 = fmaxf(a7 * dv + bb1.w, 0.f);
  float s1 = ((v0 + v1) + (v2 + v3)) + ((v4 + v5) + (v6 + v7));
  float s2 = ((v0 * v0 + v1 * v1) + (v2 * v2 + v3 * v3)) +
             ((v4 * v4 + v5 * v5) + (v6 * v6 + v7 * v7));
#pragma unroll
  for (int off = 1; off < 16; off <<= 1) {  // LN reduce within 16-lane group
    s1 += __shfl_xor(s1, off, 64);
    s2 += __shfl_xor(s2, off, 64);
  }
  float mu = s1 * (1.f / 128.f);
  float var = s2 * (1.f / 128.f) - mu * mu;
  float rs = rsqrtf(var + 1e-5f);
  float4 gg0 = ((const float4*)lng)[dq * 2];
  float4 gg1 = ((const float4*)lng)[dq * 2 + 1];
  float4 nb0 = ((const float4*)lnb)[dq * 2];
  float4 nb1 = ((const float4*)lnb)[dq * 2 + 1];
  float h0 = (v0 - mu) * rs * gg0.x + nb0.x;
  float h1 = (v1 - mu) * rs * gg0.y + nb0.y;
  float h2_ = (v2 - mu) * rs * gg0.z + nb0.z;
  float h3 = (v3 - mu) * rs * gg0.w + nb0.w;
  float h4 = (v4 - mu) * rs * gg1.x + nb1.x;
  float h5 = (v5 - mu) * rs * gg1.y + nb1.y;
  float h6 = (v6 - mu) * rs * gg1.z + nb1.z;
  float h7 = (v7 - mu) * rs * gg1.w + nb1.w;
  float4 ua = ((const float4*)wu)[dq * 2], ub = ((const float4*)wu)[dq * 2 + 1];
  float4 va = ((const float4*)wv)[dq * 2], vb = ((const float4*)wv)[dq * 2 + 1];
  float pu = ((h0 * ua.x + h1 * ua.y) + (h2_ * ua.z + h3 * ua.w)) +
             ((h4 * ub.x + h5 * ub.y) + (h6 * ub.z + h7 * ub.w));
  float pv = ((h0 * va.x + h1 * va.y) + (h2_ * va.z + h3 * va.w)) +
             ((h4 * vb.x + h5 * vb.y) + (h6 * vb.z + h7 * vb.w));
#pragma unroll
  for (int off = 1; off < 16; off <<= 1) {  // reduce over dq within group
    pu += __shfl_xor(pu, off, 64);
    pv += __shfl_xor(pv, off, 64);
  }
  if (lane == 0) tuv[v] = make_float2(pu * dv, pv * dv);  // tu, tv
}

// wave/node: 32 groups x 2 lanes; 8B float2 gather from L2-resident tuv,
// over the pre-sorted row -> deterministic order.
__global__ __launch_bounds__(256) void agg2(const float2* __restrict__ tuv,
                                            const int* __restrict__ cnt_a,
                                            const int* __restrict__ colsrc,
                                            const float* __restrict__ dinv,
                                            const float* __restrict__ cvals,
                                            float* __restrict__ Su,
                                            float* __restrict__ Sv, int N) {
  int v = blockIdx.x * 4 + (threadIdx.x >> 6);
  int lane = threadIdx.x & 63;
  if (v >= N) return;
  int g = lane >> 1, q = lane & 1;
  int cnt = cnt_a[v];
  int myidx = (lane < cnt) ? colsrc[(size_t)v * 64 + lane] : 0;
  float acc = 0.f;
  if (g == 0) {  // self loop
    float2 ts = tuv[v];
    acc = q ? ts.y : ts.x;
  }
  for (int i = 0; i < cnt; i += 32) {
    int slot = i + g;
    int s = __shfl(myidx, max(min(slot, cnt - 1), 0), 64);
    float2 m = tuv[s];
    if (slot < cnt) acc += q ? m.y : m.x;
  }
#pragma unroll
  for (int off = 2; off < 64; off <<= 1) acc += __shfl_xor(acc, off, 64);
  if (lane < 2) {
    float r = acc * dinv[v] + cvals[q];
    if (q == 0) Su[v] = r;
    else Sv[v] = r;
  }
}

__global__ __launch_bounds__(256) void decode(const int* __restrict__ eli,
                                              const float* __restrict__ Su,
                                              const float* __restrict__ Sv,
                                              const float* __restrict__ cvals,
                                              float* __restrict__ out, int EL) {
  int l = blockIdx.x * 256 + threadIdx.x;
  if (l >= EL) return;
  out[l] = Su[eli[l]] + Sv[eli[EL + l]] + cvals[2];
}

extern "C" void kernel_launch(void* const* d_in, const int* in_sizes, int n_in,
                              void* d_out, int out_size, void* d_ws, size_t ws_size,
                              hipStream_t stream) {
  const int* x = (const int*)d_in[0];
  const int* ei = (const int*)d_in[1];
  const int* eli = (const int*)d_in[2];
  const float* emb = (const float*)d_in[3];
  const float* W1 = (const float*)d_in[4];
  const float* b1 = (const float*)d_in[5];
  const float* lng = (const float*)d_in[6];
  const float* lnb = (const float*)d_in[7];
  const float* W2 = (const float*)d_in[8];
  const float* b2 = (const float*)d_in[9];
  const float* L1 = (const float*)d_in[10];
  const float* bl1 = (const float*)d_in[11];
  const float* L2 = (const float*)d_in[12];
  const float* bl2 = (const float*)d_in[13];

  int N = in_sizes[0];
  int E = in_sizes[1] / 2;
  int EL = in_sizes[2] / 2;
  const int* src = ei;
  const int* dst = ei + E;

  int NB = (N + 1023) >> 10;            // 1024-node dst slices
  int qcap = E / NB + 4096;             // Poisson slack

  char* ws = (char*)d_ws;
  auto align256 = [](size_t v) { return (v + 255) & ~(size_t)255; };
  size_t p = 0;
  int* qcur = (int*)(ws + p); p += 4096;
  int* cnt = (int*)(ws + p); p += align256((size_t)N * 4);
  float* dinv = (float*)(ws + p); p += align256((size_t)N * 4);
  ushort* wfrag = (ushort*)(ws + p); p += align256(16384 * 2);
  float* wu = (float*)(ws + p); p += 512;
  float* wv = (float*)(ws + p); p += 512;
  float* cvals = (float*)(ws + p); p += 256;
  int* colsrc = (int*)(ws + p); p += align256((size_t)N * 64 * 4);
  unsigned* queues = (unsigned*)(ws + p); p += align256((size_t)NB * qcap * 4);
  unsigned* h1b = (unsigned*)(ws + p); p += align256((size_t)N * 64 * 4);
  float2* tuv = (float2*)(ws + p); p += align256((size_t)N * 8);
  float* Su = (float*)(ws + p); p += align256((size_t)N * 4);
  float* Sv = (float*)(ws + p); p += align256((size_t)N * 4);
  (void)ws_size; (void)n_in; (void)out_size;

  prep<<<65, 256, 0, stream>>>(W1, W2, b2, L1, L2, bl1, bl2, wfrag, wu, wv,
                               cvals, qcur);
  bucket_edges<<<512, 256, 0, stream>>>(src, dst, E, NB, qcur, queues, qcap);
  scatter_ell<<<NB, 1024, 0, stream>>>(queues, qcur, qcap, cnt, dinv, colsrc, N);
  gemm1_mfma<<<(N + 127) / 128, 256, 0, stream>>>(x, emb, wfrag, dinv, h1b, N);
  agg1_ln<<<(N + 3) / 4, 256, 0, stream>>>(h1b, cnt, colsrc, dinv, b1, lng, lnb,
                                           wu, wv, tuv, N);
  agg2<<<(N + 3) / 4, 256, 0, stream>>>(tuv, cnt, colsrc, dinv, cvals, Su, Sv, N);
  decode<<<(EL + 255) / 256, 256, 0, stream>>>(eli, Su, Sv, cvals, (float*)d_out, EL);
}

// Round 17
// 168.144 us; speedup vs baseline: 1.4377x; 1.4377x over previous
//
#include <hip/hip_runtime.h>

// ---------------------------------------------------------------------------
// GCN link prediction forward on MI355X.  R17: determinism via FIXED-POINT
// (order-invariant integer sums) instead of sorting. Integer addition is
// exactly associative, so the nondeterministic colsrc fill order cannot
// affect any output bit. No sort pass (R15's cost 18.7us standalone, R16's
// fused variant 100us at 15% occ — both gone).
//   h1i[n][d]  = int16(round((emb[x]@W1)[d] * dinv[n] * 2^11))   [gemm1]
//   agg1: int32 sums -> LN (fp32 regs) -> tu/tv dots -> tuvi int2 @2^20
//   agg2: int32 sums of tuvi -> Su/Sv fp32
//   out[l] = Su[a] + Sv[b] + c0
// Linear collapse (R12): w=L1@L2, u=w[:16], v=w[16:], wu=W2@u, wv=W2@v,
// gemm2/decode-MLP algebraically folded away.
// agg1 gather is at the 8-XCD L2-replication floor (~190MB @ ~2.9TB/s);
// R7/R8/R10/R11 probed dim-split/fusion/depth/sort-locality — all null.
// ---------------------------------------------------------------------------

typedef __attribute__((ext_vector_type(8))) __bf16 bf16x8;
typedef __attribute__((ext_vector_type(4))) float f32x4;

// blocks 0..63: W1 fragment table. block 64: linear-collapse constants + qcur=0.
__global__ __launch_bounds__(256) void prep(const float* __restrict__ W1,
                                            const float* __restrict__ W2,
                                            const float* __restrict__ b2,
                                            const float* __restrict__ L1,
                                            const float* __restrict__ L2,
                                            const float* __restrict__ bl1,
                                            const float* __restrict__ bl2,
                                            ushort* __restrict__ wfrag,
                                            float* __restrict__ wu,
                                            float* __restrict__ wv,
                                            float* __restrict__ cvals,
                                            int* __restrict__ qcur) {
  int t = threadIdx.x;
  if (blockIdx.x < 64) {
    int idx = blockIdx.x * 256 + t;  // 16384 elements
    int j = idx & 7, lane = (idx >> 3) & 63, ct = (idx >> 9) & 7, kt = idx >> 12;
    int k = kt * 32 + (lane >> 4) * 8 + j;
    int col = ct * 16 + (lane & 15);
    __bf16 h = (__bf16)W1[k * 128 + col];
    wfrag[idx] = __builtin_bit_cast(ushort, h);
    return;
  }
  for (int i = t; i < 1024; i += 256) qcur[i] = 0;
  __shared__ float us[32];  // w = L1@L2
  if (t < 32) {
    float a = 0.f;
    for (int j = 0; j < 16; ++j) a += L1[t * 16 + j] * L2[j];
    us[t] = a;
  }
  __syncthreads();
  if (t < 128) {
    float a = 0.f, b = 0.f;
    for (int k = 0; k < 16; ++k) {
      float w = W2[t * 16 + k];
      a += w * us[k];
      b += w * us[16 + k];
    }
    wu[t] = a;
    wv[t] = b;
  } else if (t == 128) {
    float a = 0.f;
    for (int k = 0; k < 16; ++k) a += b2[k] * us[k];
    cvals[0] = a;  // cu
  } else if (t == 129) {
    float a = 0.f;
    for (int k = 0; k < 16; ++k) a += b2[k] * us[16 + k];
    cvals[1] = a;  // cv
  } else if (t == 130) {
    float a = 0.f;
    for (int j = 0; j < 16; ++j) a += bl1[j] * L2[j];
    cvals[2] = a + bl2[0];  // c0
  }
}

// Pass 1: read edges once, route to NB per-slice queues (slice = 1024 dsts).
// Entry = src | (localdst << 22).
__global__ __launch_bounds__(256) void bucket_edges(const int* __restrict__ src,
                                                    const int* __restrict__ dst,
                                                    int E, int NB,
                                                    int* __restrict__ qcur,
                                                    unsigned* __restrict__ queues,
                                                    int qcap) {
  __shared__ int lcnt[128];
  __shared__ int lbase[128];
  int t = threadIdx.x;
  int CH = (E + gridDim.x - 1) / gridDim.x;
  int beg = blockIdx.x * CH;
  int end = min(E, beg + CH);
  for (int i = t; i < NB; i += 256) lcnt[i] = 0;
  __syncthreads();
  for (int e = beg + t; e < end; e += 256) atomicAdd(&lcnt[dst[e] >> 10], 1);
  __syncthreads();
  for (int i = t; i < NB; i += 256) {
    lbase[i] = atomicAdd(&qcur[i], lcnt[i]);
    lcnt[i] = 0;
  }
  __syncthreads();
  for (int e = beg + t; e < end; e += 256) {  // chunk is L2-hot now
    int d = dst[e];
    int p = d >> 10;
    int pos = lbase[p] + atomicAdd(&lcnt[p], 1);
    if (pos < qcap)
      queues[(size_t)p * qcap + pos] =
          (unsigned)src[e] | ((unsigned)(d - (p << 10)) << 22);
  }
}

// Pass 2: one block per slice; cnt slice lives in LDS; emits cnt+dinv.
// Fill order nondeterministic — harmless: downstream sums are integer.
__global__ __launch_bounds__(1024) void scatter_ell(const unsigned* __restrict__ queues,
                                                    const int* __restrict__ qcur,
                                                    int qcap, int* __restrict__ cnt,
                                                    float* __restrict__ dinv,
                                                    int* __restrict__ colsrc, int N) {
  __shared__ int lcnt[1024];
  int b = blockIdx.x, t = threadIdx.x;
  lcnt[t] = 0;
  __syncthreads();
  int len = min(qcur[b], qcap);
  const unsigned* q = queues + (size_t)b * qcap;
  int lo = b << 10;
  for (int i = t; i < len; i += 1024) {
    unsigned u = q[i];
    unsigned ld = u >> 22;
    int pos = atomicAdd(&lcnt[ld], 1);
    if (pos < 64) colsrc[(size_t)(lo + ld) * 64 + pos] = (int)(u & 0x3FFFFFu);
  }
  __syncthreads();
  int node = lo + t;
  if (node < N) {
    int c = min(lcnt[t], 64);
    cnt[node] = c;
    dinv[node] = rsqrtf((float)(c + 1));
  }
}

// h1i[node][dim] int16 = round((emb[x[node]] @ W1) * dinv[node] * 2^11),
// via 16x16x32 MFMA. int16 @2^11 has finer quantization than bf16 here.
__global__ __launch_bounds__(256) void gemm1_mfma(
    const int* __restrict__ x, const float* __restrict__ emb,
    const ushort* __restrict__ wfrag, const float* __restrict__ dinv,
    unsigned* __restrict__ h1i, int N) {
  __shared__ alignas(16) ushort Wlds[16384];  // 32 KB frag table
  int t = threadIdx.x;
  for (int i = t; i < 2048; i += 256)
    ((uint4*)Wlds)[i] = ((const uint4*)wfrag)[i];
  __syncthreads();
  int w = t >> 6, lane = t & 63;
  int row0 = blockIdx.x * 128 + w * 32;  // this wave: nodes row0..row0+31
  int rB = lane & 15, kg = lane >> 4;
  int n0 = row0 + rB, n1 = row0 + 16 + rB;
  const float* e0 = emb + (size_t)x[min(n0, N - 1)] * 128 + kg * 8;
  const float* e1 = emb + (size_t)x[min(n1, N - 1)] * 128 + kg * 8;
  f32x4 acc[2][8];
#pragma unroll
  for (int g = 0; g < 2; ++g)
#pragma unroll
    for (int ct = 0; ct < 8; ++ct) acc[g][ct] = (f32x4)(0.f);
#pragma unroll
  for (int kt = 0; kt < 4; ++kt) {
    float4 p0 = *(const float4*)(e0 + kt * 32);
    float4 p1 = *(const float4*)(e0 + kt * 32 + 4);
    float4 q0 = *(const float4*)(e1 + kt * 32);
    float4 q1 = *(const float4*)(e1 + kt * 32 + 4);
    bf16x8 fb0, fb1;
    fb0[0] = (__bf16)p0.x; fb0[1] = (__bf16)p0.y; fb0[2] = (__bf16)p0.z; fb0[3] = (__bf16)p0.w;
    fb0[4] = (__bf16)p1.x; fb0[5] = (__bf16)p1.y; fb0[6] = (__bf16)p1.z; fb0[7] = (__bf16)p1.w;
    fb1[0] = (__bf16)q0.x; fb1[1] = (__bf16)q0.y; fb1[2] = (__bf16)q0.z; fb1[3] = (__bf16)q0.w;
    fb1[4] = (__bf16)q1.x; fb1[5] = (__bf16)q1.y; fb1[6] = (__bf16)q1.z; fb1[7] = (__bf16)q1.w;
#pragma unroll
    for (int ct = 0; ct < 8; ++ct) {
      bf16x8 wv = *(const bf16x8*)&Wlds[((kt * 8 + ct) * 64 + lane) * 8];
      acc[0][ct] = __builtin_amdgcn_mfma_f32_16x16x32_bf16(wv, fb0, acc[0][ct], 0, 0, 0);
      acc[1][ct] = __builtin_amdgcn_mfma_f32_16x16x32_bf16(wv, fb1, acc[1][ct], 0, 0, 0);
    }
  }
#pragma unroll
  for (int g = 0; g < 2; ++g) {
    int node = row0 + g * 16 + rB;
    if (node < N) {
      float dv2 = dinv[node] * 2048.f;
#pragma unroll
      for (int ct = 0; ct < 8; ++ct) {
        f32x4 a = acc[g][ct];
        int q0 = max(min((int)rintf(a[0] * dv2), 32767), -32767);
        int q1 = max(min((int)rintf(a[1] * dv2), 32767), -32767);
        int q2 = max(min((int)rintf(a[2] * dv2), 32767), -32767);
        int q3 = max(min((int)rintf(a[3] * dv2), 32767), -32767);
        uint2 o;
        o.x = ((unsigned)q0 & 0xFFFFu) | ((unsigned)q1 << 16);
        o.y = ((unsigned)q2 & 0xFFFFu) | ((unsigned)q3 << 16);
        *(uint2*)&h1i[(size_t)node * 64 + ct * 8 + kg * 2] = o;
      }
    }
  }
}

// wave/node: lane=(g,dq) g in [0,4), dq in [0,16); 16B/lane, 4-deep gather
// pipeline. INTEGER accumulation (order-invariant). Epilogue: LN in fp32
// regs, tu/tv dots vs wu/wv, write tuvi (int2 @2^20, clamp +-30).
__global__ __launch_bounds__(256) void agg1_ln(const unsigned* __restrict__ h1i,
                                               const int* __restrict__ cnt_a,
                                               const int* __restrict__ colsrc,
                                               const float* __restrict__ dinv,
                                               const float* __restrict__ b1,
                                               const float* __restrict__ lng,
                                               const float* __restrict__ lnb,
                                               const float* __restrict__ wu,
                                               const float* __restrict__ wv,
                                               int2* __restrict__ tuvi, int N) {
  int v = blockIdx.x * 4 + (threadIdx.x >> 6);
  int lane = threadIdx.x & 63;
  if (v >= N) return;
  int g = lane >> 4, dq = lane & 15;
  const uint4* tb = (const uint4*)h1i;  // row = 16 x uint4
  int cnt = cnt_a[v];
  int myidx = (lane < cnt) ? colsrc[(size_t)v * 64 + lane] : 0;
  int a0 = 0, a1 = 0, a2 = 0, a3 = 0, a4 = 0, a5 = 0, a6 = 0, a7 = 0;
#define ACC1(m)                                              \
  {                                                          \
    a0 += ((int)(m.x << 16)) >> 16; a1 += ((int)m.x) >> 16;  \
    a2 += ((int)(m.y << 16)) >> 16; a3 += ((int)m.y) >> 16;  \
    a4 += ((int)(m.z << 16)) >> 16; a5 += ((int)m.z) >> 16;  \
    a6 += ((int)(m.w << 16)) >> 16; a7 += ((int)m.w) >> 16;  \
  }
  if (g == 0) {  // self loop (pre-scaled)
    uint4 ms = tb[(size_t)v * 16 + dq];
    ACC1(ms);
  }
  int i = 0;
  for (; i + 16 <= cnt; i += 16) {  // 16 rows in flight across the wave
    int s0 = __shfl(myidx, i + g, 64);
    int s1_ = __shfl(myidx, i + 4 + g, 64);
    int s2_ = __shfl(myidx, i + 8 + g, 64);
    int s3_ = __shfl(myidx, i + 12 + g, 64);
    uint4 m0 = tb[(size_t)s0 * 16 + dq];
    uint4 m1 = tb[(size_t)s1_ * 16 + dq];
    uint4 m2 = tb[(size_t)s2_ * 16 + dq];
    uint4 m3 = tb[(size_t)s3_ * 16 + dq];
    ACC1(m0);
    ACC1(m1);
    ACC1(m2);
    ACC1(m3);
  }
  {  // tail: 4 predicated steps cover all <=15 remaining slots
    int slot0 = i + g, slot1 = i + 4 + g, slot2 = i + 8 + g, slot3 = i + 12 + g;
    int c1 = max(cnt - 1, 0);
    int t0 = __shfl(myidx, min(slot0, c1), 64);
    int t1 = __shfl(myidx, min(slot1, c1), 64);
    int t2 = __shfl(myidx, min(slot2, c1), 64);
    int t3 = __shfl(myidx, min(slot3, c1), 64);
    if (slot0 < cnt) { uint4 m = tb[(size_t)t0 * 16 + dq]; ACC1(m); }
    if (slot1 < cnt) { uint4 m = tb[(size_t)t1 * 16 + dq]; ACC1(m); }
    if (slot2 < cnt) { uint4 m = tb[(size_t)t2 * 16 + dq]; ACC1(m); }
    if (slot3 < cnt) { uint4 m = tb[(size_t)t3 * 16 + dq]; ACC1(m); }
  }
#undef ACC1
#pragma unroll
  for (int off = 16; off < 64; off <<= 1) {  // cross-group reduce (int, exact)
    a0 += __shfl_xor(a0, off, 64);
    a1 += __shfl_xor(a1, off, 64);
    a2 += __shfl_xor(a2, off, 64);
    a3 += __shfl_xor(a3, off, 64);
    a4 += __shfl_xor(a4, off, 64);
    a5 += __shfl_xor(a5, off, 64);
    a6 += __shfl_xor(a6, off, 64);
    a7 += __shfl_xor(a7, off, 64);
  }
  float dv = dinv[v];
  float dvq = dv * (1.f / 2048.f);
  float4 bb0 = ((const float4*)b1)[dq * 2];
  float4 bb1 = ((const float4*)b1)[dq * 2 + 1];
  float v0 = fmaxf((float)a0 * dvq + bb0.x, 0.f);
  float v1 = fmaxf((float)a1 * dvq + bb0.y, 0.f);
  float v2 = fmaxf((float)a2 * dvq + bb0.z, 0.f);
  float v3 = fmaxf((float)a3 * dvq + bb0.w, 0.f);
  float v4 = fmaxf((float)a4 * dvq + bb1.x, 0.f);
  float v5 = fmaxf((float)a5 * dvq + bb1.y, 0.f);
  float v6 = fmaxf((float)a6 * dvq + bb1.z, 0.f);
  float v7 = fmaxf((float)a7 * dvq + bb1.w, 0.f);
  float s1 = ((v0 + v1) + (v2 + v3)) + ((v4 + v5) + (v6 + v7));
  float s2 = ((v0 * v0 + v1 * v1) + (v2 * v2 + v3 * v3)) +
             ((v4 * v4 + v5 * v5) + (v6 * v6 + v7 * v7));
#pragma unroll
  for (int off = 1; off < 16; off <<= 1) {  // LN reduce within 16-lane group
    s1 += __shfl_xor(s1, off, 64);
    s2 += __shfl_xor(s2, off, 64);
  }
  float mu = s1 * (1.f / 128.f);
  float var = s2 * (1.f / 128.f) - mu * mu;
  float rs = rsqrtf(var + 1e-5f);
  float4 gg0 = ((const float4*)lng)[dq * 2];
  float4 gg1 = ((const float4*)lng)[dq * 2 + 1];
  float4 nb0 = ((const float4*)lnb)[dq * 2];
  float4 nb1 = ((const float4*)lnb)[dq * 2 + 1];
  float h0 = (v0 - mu) * rs * gg0.x + nb0.x;
  float h1 = (v1 - mu) * rs * gg0.y + nb0.y;
  float h2_ = (v2 - mu) * rs * gg0.z + nb0.z;
  float h3 = (v3 - mu) * rs * gg0.w + nb0.w;
  float h4 = (v4 - mu) * rs * gg1.x + nb1.x;
  float h5 = (v5 - mu) * rs * gg1.y + nb1.y;
  float h6 = (v6 - mu) * rs * gg1.z + nb1.z;
  float h7 = (v7 - mu) * rs * gg1.w + nb1.w;
  float4 ua = ((const float4*)wu)[dq * 2], ub = ((const float4*)wu)[dq * 2 + 1];
  float4 va = ((const float4*)wv)[dq * 2], vb = ((const float4*)wv)[dq * 2 + 1];
  float pu = ((h0 * ua.x + h1 * ua.y) + (h2_ * ua.z + h3 * ua.w)) +
             ((h4 * ub.x + h5 * ub.y) + (h6 * ub.z + h7 * ub.w));
  float pv = ((h0 * va.x + h1 * va.y) + (h2_ * va.z + h3 * va.w)) +
             ((h4 * vb.x + h5 * vb.y) + (h6 * vb.z + h7 * vb.w));
#pragma unroll
  for (int off = 1; off < 16; off <<= 1) {  // reduce over dq within group
    pu += __shfl_xor(pu, off, 64);
    pv += __shfl_xor(pv, off, 64);
  }
  if (lane == 0) {
    float tu_ = fminf(fmaxf(pu * dv, -30.f), 30.f);
    float tv_ = fminf(fmaxf(pv * dv, -30.f), 30.f);
    int2 o;
    o.x = (int)rintf(tu_ * 1048576.f);
    o.y = (int)rintf(tv_ * 1048576.f);
    tuvi[v] = o;
  }
}

// wave/node: 32 groups x 2 lanes; 8B int2 gather from L2-resident tuvi.
// Integer sums -> order-invariant -> deterministic.
__global__ __launch_bounds__(256) void agg2(const int2* __restrict__ tuvi,
                                            const int* __restrict__ cnt_a,
                                            const int* __restrict__ colsrc,
                                            const float* __restrict__ dinv,
                                            const float* __restrict__ cvals,
                                            float* __restrict__ Su,
                                            float* __restrict__ Sv, int N) {
  int v = blockIdx.x * 4 + (threadIdx.x >> 6);
  int lane = threadIdx.x & 63;
  if (v >= N) return;
  int g = lane >> 1, q = lane & 1;
  int cnt = cnt_a[v];
  int myidx = (lane < cnt) ? colsrc[(size_t)v * 64 + lane] : 0;
  int acc = 0;
  if (g == 0) {  // self loop
    int2 ts = tuvi[v];
    acc = q ? ts.y : ts.x;
  }
  for (int i = 0; i < cnt; i += 32) {
    int slot = i + g;
    int s = __shfl(myidx, max(min(slot, cnt - 1), 0), 64);
    int2 m = tuvi[s];
    if (slot < cnt) acc += q ? m.y : m.x;
  }
#pragma unroll
  for (int off = 2; off < 64; off <<= 1) acc += __shfl_xor(acc, off, 64);
  if (lane < 2) {
    float r = (float)acc * (1.f / 1048576.f) * dinv[v] + cvals[q];
    if (q == 0) Su[v] = r;
    else Sv[v] = r;
  }
}

__global__ __launch_bounds__(256) void decode(const int* __restrict__ eli,
                                              const float* __restrict__ Su,
                                              const float* __restrict__ Sv,
                                              const float* __restrict__ cvals,
                                              float* __restrict__ out, int EL) {
  int l = blockIdx.x * 256 + threadIdx.x;
  if (l >= EL) return;
  out[l] = Su[eli[l]] + Sv[eli[EL + l]] + cvals[2];
}

extern "C" void kernel_launch(void* const* d_in, const int* in_sizes, int n_in,
                              void* d_out, int out_size, void* d_ws, size_t ws_size,
                              hipStream_t stream) {
  const int* x = (const int*)d_in[0];
  const int* ei = (const int*)d_in[1];
  const int* eli = (const int*)d_in[2];
  const float* emb = (const float*)d_in[3];
  const float* W1 = (const float*)d_in[4];
  const float* b1 = (const float*)d_in[5];
  const float* lng = (const float*)d_in[6];
  const float* lnb = (const float*)d_in[7];
  const float* W2 = (const float*)d_in[8];
  const float* b2 = (const float*)d_in[9];
  const float* L1 = (const float*)d_in[10];
  const float* bl1 = (const float*)d_in[11];
  const float* L2 = (const float*)d_in[12];
  const float* bl2 = (const float*)d_in[13];

  int N = in_sizes[0];
  int E = in_sizes[1] / 2;
  int EL = in_sizes[2] / 2;
  const int* src = ei;
  const int* dst = ei + E;

  int NB = (N + 1023) >> 10;            // 1024-node dst slices
  int qcap = E / NB + 4096;             // Poisson slack

  char* ws = (char*)d_ws;
  auto align256 = [](size_t v) { return (v + 255) & ~(size_t)255; };
  size_t p = 0;
  int* qcur = (int*)(ws + p); p += 4096;
  int* cnt = (int*)(ws + p); p += align256((size_t)N * 4);
  float* dinv = (float*)(ws + p); p += align256((size_t)N * 4);
  ushort* wfrag = (ushort*)(ws + p); p += align256(16384 * 2);
  float* wu = (float*)(ws + p); p += 512;
  float* wv = (float*)(ws + p); p += 512;
  float* cvals = (float*)(ws + p); p += 256;
  int* colsrc = (int*)(ws + p); p += align256((size_t)N * 64 * 4);
  unsigned* queues = (unsigned*)(ws + p); p += align256((size_t)NB * qcap * 4);
  unsigned* h1i = (unsigned*)(ws + p); p += align256((size_t)N * 64 * 4);
  int2* tuvi = (int2*)(ws + p); p += align256((size_t)N * 8);
  float* Su = (float*)(ws + p); p += align256((size_t)N * 4);
  float* Sv = (float*)(ws + p); p += align256((size_t)N * 4);
  (void)ws_size; (void)n_in; (void)out_size;

  prep<<<65, 256, 0, stream>>>(W1, W2, b2, L1, L2, bl1, bl2, wfrag, wu, wv,
                               cvals, qcur);
  bucket_edges<<<512, 256, 0, stream>>>(src, dst, E, NB, qcur, queues, qcap);
  scatter_ell<<<NB, 1024, 0, stream>>>(queues, qcur, qcap, cnt, dinv, colsrc, N);
  gemm1_mfma<<<(N + 127) / 128, 256, 0, stream>>>(x, emb, wfrag, dinv, h1i, N);
  agg1_ln<<<(N + 3) / 4, 256, 0, stream>>>(h1i, cnt, colsrc, dinv, b1, lng, lnb,
                                           wu, wv, tuvi, N);
  agg2<<<(N + 3) / 4, 256, 0, stream>>>(tuvi, cnt, colsrc, dinv, cvals, Su, Sv, N);
  decode<<<(EL + 255) / 256, 256, 0, stream>>>(eli, Su, Sv, cvals, (float*)d_out, EL);
}

// Round 18
// 167.938 us; speedup vs baseline: 1.4395x; 1.0012x over previous
//
#include <hip/hip_runtime.h>

// ---------------------------------------------------------------------------
// GCN link prediction forward on MI355X.  R18 = R17 (fixed-point, linear
// collapse) with PACKED int16 accumulation in agg1: h1 stored int16 @2^7,
// values clamped to +-504 so any <=65-term sum <=32760 fits int16 exactly
// (no wrap) -> accumulate with v_pk_add_i16 (ext_vector short8 adds), 4 VALU
// per 8 dims instead of 16, zero per-neighbor unpacking. Order-invariant
// integer sums keep the output bitwise deterministic.
//   h1q[n][d] = clamp(round((emb[x]@W1)[d]*dinv[n]*2^7), +-504)  int16
//   agg1: short8 pk sums -> unpack once -> LN (fp32) -> tu/tv dots
//         -> tuvi int2 @2^20
//   agg2: int32 sums of tuvi -> Su/Sv fp32;  out[l] = Su[a]+Sv[b]+c0
// agg1 gather is at the 8-XCD L2-replication floor (~190MB @ ~2.9TB/s).
// ---------------------------------------------------------------------------

typedef __attribute__((ext_vector_type(8))) __bf16 bf16x8;
typedef __attribute__((ext_vector_type(4))) float f32x4;
typedef __attribute__((ext_vector_type(8))) short s16x8;

// blocks 0..63: W1 fragment table. block 64: linear-collapse constants + qcur=0.
__global__ __launch_bounds__(256) void prep(const float* __restrict__ W1,
                                            const float* __restrict__ W2,
                                            const float* __restrict__ b2,
                                            const float* __restrict__ L1,
                                            const float* __restrict__ L2,
                                            const float* __restrict__ bl1,
                                            const float* __restrict__ bl2,
                                            ushort* __restrict__ wfrag,
                                            float* __restrict__ wu,
                                            float* __restrict__ wv,
                                            float* __restrict__ cvals,
                                            int* __restrict__ qcur) {
  int t = threadIdx.x;
  if (blockIdx.x < 64) {
    int idx = blockIdx.x * 256 + t;  // 16384 elements
    int j = idx & 7, lane = (idx >> 3) & 63, ct = (idx >> 9) & 7, kt = idx >> 12;
    int k = kt * 32 + (lane >> 4) * 8 + j;
    int col = ct * 16 + (lane & 15);
    __bf16 h = (__bf16)W1[k * 128 + col];
    wfrag[idx] = __builtin_bit_cast(ushort, h);
    return;
  }
  for (int i = t; i < 1024; i += 256) qcur[i] = 0;
  __shared__ float us[32];  // w = L1@L2
  if (t < 32) {
    float a = 0.f;
    for (int j = 0; j < 16; ++j) a += L1[t * 16 + j] * L2[j];
    us[t] = a;
  }
  __syncthreads();
  if (t < 128) {
    float a = 0.f, b = 0.f;
    for (int k = 0; k < 16; ++k) {
      float w = W2[t * 16 + k];
      a += w * us[k];
      b += w * us[16 + k];
    }
    wu[t] = a;
    wv[t] = b;
  } else if (t == 128) {
    float a = 0.f;
    for (int k = 0; k < 16; ++k) a += b2[k] * us[k];
    cvals[0] = a;  // cu
  } else if (t == 129) {
    float a = 0.f;
    for (int k = 0; k < 16; ++k) a += b2[k] * us[16 + k];
    cvals[1] = a;  // cv
  } else if (t == 130) {
    float a = 0.f;
    for (int j = 0; j < 16; ++j) a += bl1[j] * L2[j];
    cvals[2] = a + bl2[0];  // c0
  }
}

// Pass 1: read edges once, route to NB per-slice queues (slice = 1024 dsts).
// Entry = src | (localdst << 22).
__global__ __launch_bounds__(256) void bucket_edges(const int* __restrict__ src,
                                                    const int* __restrict__ dst,
                                                    int E, int NB,
                                                    int* __restrict__ qcur,
                                                    unsigned* __restrict__ queues,
                                                    int qcap) {
  __shared__ int lcnt[128];
  __shared__ int lbase[128];
  int t = threadIdx.x;
  int CH = (E + gridDim.x - 1) / gridDim.x;
  int beg = blockIdx.x * CH;
  int end = min(E, beg + CH);
  for (int i = t; i < NB; i += 256) lcnt[i] = 0;
  __syncthreads();
  for (int e = beg + t; e < end; e += 256) atomicAdd(&lcnt[dst[e] >> 10], 1);
  __syncthreads();
  for (int i = t; i < NB; i += 256) {
    lbase[i] = atomicAdd(&qcur[i], lcnt[i]);
    lcnt[i] = 0;
  }
  __syncthreads();
  for (int e = beg + t; e < end; e += 256) {  // chunk is L2-hot now
    int d = dst[e];
    int p = d >> 10;
    int pos = lbase[p] + atomicAdd(&lcnt[p], 1);
    if (pos < qcap)
      queues[(size_t)p * qcap + pos] =
          (unsigned)src[e] | ((unsigned)(d - (p << 10)) << 22);
  }
}

// Pass 2: one block per slice; cnt slice lives in LDS; emits cnt+dinv.
// Fill order nondeterministic — harmless: downstream sums are integer.
__global__ __launch_bounds__(1024) void scatter_ell(const unsigned* __restrict__ queues,
                                                    const int* __restrict__ qcur,
                                                    int qcap, int* __restrict__ cnt,
                                                    float* __restrict__ dinv,
                                                    int* __restrict__ colsrc, int N) {
  __shared__ int lcnt[1024];
  int b = blockIdx.x, t = threadIdx.x;
  lcnt[t] = 0;
  __syncthreads();
  int len = min(qcur[b], qcap);
  const unsigned* q = queues + (size_t)b * qcap;
  int lo = b << 10;
  for (int i = t; i < len; i += 1024) {
    unsigned u = q[i];
    unsigned ld = u >> 22;
    int pos = atomicAdd(&lcnt[ld], 1);
    if (pos < 64) colsrc[(size_t)(lo + ld) * 64 + pos] = (int)(u & 0x3FFFFFu);
  }
  __syncthreads();
  int node = lo + t;
  if (node < N) {
    int c = min(lcnt[t], 64);
    cnt[node] = c;
    dinv[node] = rsqrtf((float)(c + 1));
  }
}

// h1q[node][dim] int16 = clamp(round((emb[x]@W1)*dinv*2^7), +-504),
// via 16x16x32 MFMA. Clamp guarantees <=65-term sums fit int16 exactly.
__global__ __launch_bounds__(256) void gemm1_mfma(
    const int* __restrict__ x, const float* __restrict__ emb,
    const ushort* __restrict__ wfrag, const float* __restrict__ dinv,
    unsigned* __restrict__ h1q, int N) {
  __shared__ alignas(16) ushort Wlds[16384];  // 32 KB frag table
  int t = threadIdx.x;
  for (int i = t; i < 2048; i += 256)
    ((uint4*)Wlds)[i] = ((const uint4*)wfrag)[i];
  __syncthreads();
  int w = t >> 6, lane = t & 63;
  int row0 = blockIdx.x * 128 + w * 32;  // this wave: nodes row0..row0+31
  int rB = lane & 15, kg = lane >> 4;
  int n0 = row0 + rB, n1 = row0 + 16 + rB;
  const float* e0 = emb + (size_t)x[min(n0, N - 1)] * 128 + kg * 8;
  const float* e1 = emb + (size_t)x[min(n1, N - 1)] * 128 + kg * 8;
  f32x4 acc[2][8];
#pragma unroll
  for (int g = 0; g < 2; ++g)
#pragma unroll
    for (int ct = 0; ct < 8; ++ct) acc[g][ct] = (f32x4)(0.f);
#pragma unroll
  for (int kt = 0; kt < 4; ++kt) {
    float4 p0 = *(const float4*)(e0 + kt * 32);
    float4 p1 = *(const float4*)(e0 + kt * 32 + 4);
    float4 q0 = *(const float4*)(e1 + kt * 32);
    float4 q1 = *(const float4*)(e1 + kt * 32 + 4);
    bf16x8 fb0, fb1;
    fb0[0] = (__bf16)p0.x; fb0[1] = (__bf16)p0.y; fb0[2] = (__bf16)p0.z; fb0[3] = (__bf16)p0.w;
    fb0[4] = (__bf16)p1.x; fb0[5] = (__bf16)p1.y; fb0[6] = (__bf16)p1.z; fb0[7] = (__bf16)p1.w;
    fb1[0] = (__bf16)q0.x; fb1[1] = (__bf16)q0.y; fb1[2] = (__bf16)q0.z; fb1[3] = (__bf16)q0.w;
    fb1[4] = (__bf16)q1.x; fb1[5] = (__bf16)q1.y; fb1[6] = (__bf16)q1.z; fb1[7] = (__bf16)q1.w;
#pragma unroll
    for (int ct = 0; ct < 8; ++ct) {
      bf16x8 wv = *(const bf16x8*)&Wlds[((kt * 8 + ct) * 64 + lane) * 8];
      acc[0][ct] = __builtin_amdgcn_mfma_f32_16x16x32_bf16(wv, fb0, acc[0][ct], 0, 0, 0);
      acc[1][ct] = __builtin_amdgcn_mfma_f32_16x16x32_bf16(wv, fb1, acc[1][ct], 0, 0, 0);
    }
  }
#pragma unroll
  for (int g = 0; g < 2; ++g) {
    int node = row0 + g * 16 + rB;
    if (node < N) {
      float dv2 = dinv[node] * 128.f;
#pragma unroll
      for (int ct = 0; ct < 8; ++ct) {
        f32x4 a = acc[g][ct];
        int q0 = max(min((int)rintf(a[0] * dv2), 504), -504);
        int q1 = max(min((int)rintf(a[1] * dv2), 504), -504);
        int q2 = max(min((int)rintf(a[2] * dv2), 504), -504);
        int q3 = max(min((int)rintf(a[3] * dv2), 504), -504);
        uint2 o;
        o.x = ((unsigned)q0 & 0xFFFFu) | ((unsigned)q1 << 16);
        o.y = ((unsigned)q2 & 0xFFFFu) | ((unsigned)q3 << 16);
        *(uint2*)&h1q[(size_t)node * 64 + ct * 8 + kg * 2] = o;
      }
    }
  }
}

// wave/node: lane=(g,dq) g in [0,4), dq in [0,16); 16B/lane, 4-deep gather
// pipeline. PACKED int16 accumulation (v_pk_add_i16 via short8 adds): 4 VALU
// per 8 dims, no per-neighbor unpack. Sums provably fit int16 (clamp +-504,
// <=65 terms). Epilogue: unpack once, LN in fp32, tu/tv dots, tuvi @2^20.
__global__ __launch_bounds__(256) void agg1_ln(const unsigned* __restrict__ h1q,
                                               const int* __restrict__ cnt_a,
                                               const int* __restrict__ colsrc,
                                               const float* __restrict__ dinv,
                                               const float* __restrict__ b1,
                                               const float* __restrict__ lng,
                                               const float* __restrict__ lnb,
                                               const float* __restrict__ wu,
                                               const float* __restrict__ wv,
                                               int2* __restrict__ tuvi, int N) {
  int v = blockIdx.x * 4 + (threadIdx.x >> 6);
  int lane = threadIdx.x & 63;
  if (v >= N) return;
  int g = lane >> 4, dq = lane & 15;
  const uint4* tb = (const uint4*)h1q;  // row = 16 x uint4
  int cnt = cnt_a[v];
  int myidx = (lane < cnt) ? colsrc[(size_t)v * 64 + lane] : 0;
  s16x8 acc = (s16x8)(short)0;
  if (g == 0) {  // self loop (pre-scaled)
    uint4 ms = tb[(size_t)v * 16 + dq];
    acc += __builtin_bit_cast(s16x8, ms);
  }
  int i = 0;
  for (; i + 16 <= cnt; i += 16) {  // 16 rows in flight across the wave
    int s0 = __shfl(myidx, i + g, 64);
    int s1_ = __shfl(myidx, i + 4 + g, 64);
    int s2_ = __shfl(myidx, i + 8 + g, 64);
    int s3_ = __shfl(myidx, i + 12 + g, 64);
    uint4 m0 = tb[(size_t)s0 * 16 + dq];
    uint4 m1 = tb[(size_t)s1_ * 16 + dq];
    uint4 m2 = tb[(size_t)s2_ * 16 + dq];
    uint4 m3 = tb[(size_t)s3_ * 16 + dq];
    acc += __builtin_bit_cast(s16x8, m0);
    acc += __builtin_bit_cast(s16x8, m1);
    acc += __builtin_bit_cast(s16x8, m2);
    acc += __builtin_bit_cast(s16x8, m3);
  }
  {  // tail: 4 predicated steps cover all <=15 remaining slots
    int slot0 = i + g, slot1 = i + 4 + g, slot2 = i + 8 + g, slot3 = i + 12 + g;
    int c1 = max(cnt - 1, 0);
    int t0 = __shfl(myidx, min(slot0, c1), 64);
    int t1 = __shfl(myidx, min(slot1, c1), 64);
    int t2 = __shfl(myidx, min(slot2, c1), 64);
    int t3 = __shfl(myidx, min(slot3, c1), 64);
    if (slot0 < cnt) { uint4 m = tb[(size_t)t0 * 16 + dq]; acc += __builtin_bit_cast(s16x8, m); }
    if (slot1 < cnt) { uint4 m = tb[(size_t)t1 * 16 + dq]; acc += __builtin_bit_cast(s16x8, m); }
    if (slot2 < cnt) { uint4 m = tb[(size_t)t2 * 16 + dq]; acc += __builtin_bit_cast(s16x8, m); }
    if (slot3 < cnt) { uint4 m = tb[(size_t)t3 * 16 + dq]; acc += __builtin_bit_cast(s16x8, m); }
  }
#pragma unroll
  for (int off = 16; off < 64; off <<= 1) {  // cross-group reduce (exact)
    uint4 au = __builtin_bit_cast(uint4, acc);
    uint4 ou;
    ou.x = __shfl_xor((int)au.x, off, 64);
    ou.y = __shfl_xor((int)au.y, off, 64);
    ou.z = __shfl_xor((int)au.z, off, 64);
    ou.w = __shfl_xor((int)au.w, off, 64);
    acc += __builtin_bit_cast(s16x8, ou);
  }
  int a0 = acc[0], a1 = acc[1], a2 = acc[2], a3 = acc[3];
  int a4 = acc[4], a5 = acc[5], a6 = acc[6], a7 = acc[7];
  float dv = dinv[v];
  float dvq = dv * (1.f / 128.f);
  float4 bb0 = ((const float4*)b1)[dq * 2];
  float4 bb1 = ((const float4*)b1)[dq * 2 + 1];
  float v0 = fmaxf((float)a0 * dvq + bb0.x, 0.f);
  float v1 = fmaxf((float)a1 * dvq + bb0.y, 0.f);
  float v2 = fmaxf((float)a2 * dvq + bb0.z, 0.f);
  float v3 = fmaxf((float)a3 * dvq + bb0.w, 0.f);
  float v4 = fmaxf((float)a4 * dvq + bb1.x, 0.f);
  float v5 = fmaxf((float)a5 * dvq + bb1.y, 0.f);
  float v6 = fmaxf((float)a6 * dvq + bb1.z, 0.f);
  float v7 = fmaxf((float)a7 * dvq + bb1.w, 0.f);
  float s1 = ((v0 + v1) + (v2 + v3)) + ((v4 + v5) + (v6 + v7));
  float s2 = ((v0 * v0 + v1 * v1) + (v2 * v2 + v3 * v3)) +
             ((v4 * v4 + v5 * v5) + (v6 * v6 + v7 * v7));
#pragma unroll
  for (int off = 1; off < 16; off <<= 1) {  // LN reduce within 16-lane group
    s1 += __shfl_xor(s1, off, 64);
    s2 += __shfl_xor(s2, off, 64);
  }
  float mu = s1 * (1.f / 128.f);
  float var = s2 * (1.f / 128.f) - mu * mu;
  float rs = rsqrtf(var + 1e-5f);
  float4 gg0 = ((const float4*)lng)[dq * 2];
  float4 gg1 = ((const float4*)lng)[dq * 2 + 1];
  float4 nb0 = ((const float4*)lnb)[dq * 2];
  float4 nb1 = ((const float4*)lnb)[dq * 2 + 1];
  float h0 = (v0 - mu) * rs * gg0.x + nb0.x;
  float h1 = (v1 - mu) * rs * gg0.y + nb0.y;
  float h2_ = (v2 - mu) * rs * gg0.z + nb0.z;
  float h3 = (v3 - mu) * rs * gg0.w + nb0.w;
  float h4 = (v4 - mu) * rs * gg1.x + nb1.x;
  float h5 = (v5 - mu) * rs * gg1.y + nb1.y;
  float h6 = (v6 - mu) * rs * gg1.z + nb1.z;
  float h7 = (v7 - mu) * rs * gg1.w + nb1.w;
  float4 ua = ((const float4*)wu)[dq * 2], ub = ((const float4*)wu)[dq * 2 + 1];
  float4 va = ((const float4*)wv)[dq * 2], vb = ((const float4*)wv)[dq * 2 + 1];
  float pu = ((h0 * ua.x + h1 * ua.y) + (h2_ * ua.z + h3 * ua.w)) +
             ((h4 * ub.x + h5 * ub.y) + (h6 * ub.z + h7 * ub.w));
  float pv = ((h0 * va.x + h1 * va.y) + (h2_ * va.z + h3 * va.w)) +
             ((h4 * vb.x + h5 * vb.y) + (h6 * vb.z + h7 * vb.w));
#pragma unroll
  for (int off = 1; off < 16; off <<= 1) {  // reduce over dq within group
    pu += __shfl_xor(pu, off, 64);
    pv += __shfl_xor(pv, off, 64);
  }
  if (lane == 0) {
    float tu_ = fminf(fmaxf(pu * dv, -30.f), 30.f);
    float tv_ = fminf(fmaxf(pv * dv, -30.f), 30.f);
    int2 o;
    o.x = (int)rintf(tu_ * 1048576.f);
    o.y = (int)rintf(tv_ * 1048576.f);
    tuvi[v] = o;
  }
}

// wave/node: 32 groups x 2 lanes; 8B int2 gather from L2-resident tuvi.
// Integer sums -> order-invariant -> deterministic.
__global__ __launch_bounds__(256) void agg2(const int2* __restrict__ tuvi,
                                            const int* __restrict__ cnt_a,
                                            const int* __restrict__ colsrc,
                                            const float* __restrict__ dinv,
                                            const float* __restrict__ cvals,
                                            float* __restrict__ Su,
                                            float* __restrict__ Sv, int N) {
  int v = blockIdx.x * 4 + (threadIdx.x >> 6);
  int lane = threadIdx.x & 63;
  if (v >= N) return;
  int g = lane >> 1, q = lane & 1;
  int cnt = cnt_a[v];
  int myidx = (lane < cnt) ? colsrc[(size_t)v * 64 + lane] : 0;
  int acc = 0;
  if (g == 0) {  // self loop
    int2 ts = tuvi[v];
    acc = q ? ts.y : ts.x;
  }
  for (int i = 0; i < cnt; i += 32) {
    int slot = i + g;
    int s = __shfl(myidx, max(min(slot, cnt - 1), 0), 64);
    int2 m = tuvi[s];
    if (slot < cnt) acc += q ? m.y : m.x;
  }
#pragma unroll
  for (int off = 2; off < 64; off <<= 1) acc += __shfl_xor(acc, off, 64);
  if (lane < 2) {
    float r = (float)acc * (1.f / 1048576.f) * dinv[v] + cvals[q];
    if (q == 0) Su[v] = r;
    else Sv[v] = r;
  }
}

__global__ __launch_bounds__(256) void decode(const int* __restrict__ eli,
                                              const float* __restrict__ Su,
                                              const float* __restrict__ Sv,
                                              const float* __restrict__ cvals,
                                              float* __restrict__ out, int EL) {
  int l = blockIdx.x * 256 + threadIdx.x;
  if (l >= EL) return;
  out[l] = Su[eli[l]] + Sv[eli[EL + l]] + cvals[2];
}

extern "C" void kernel_launch(void* const* d_in, const int* in_sizes, int n_in,
                              void* d_out, int out_size, void* d_ws, size_t ws_size,
                              hipStream_t stream) {
  const int* x = (const int*)d_in[0];
  const int* ei = (const int*)d_in[1];
  const int* eli = (const int*)d_in[2];
  const float* emb = (const float*)d_in[3];
  const float* W1 = (const float*)d_in[4];
  const float* b1 = (const float*)d_in[5];
  const float* lng = (const float*)d_in[6];
  const float* lnb = (const float*)d_in[7];
  const float* W2 = (const float*)d_in[8];
  const float* b2 = (const float*)d_in[9];
  const float* L1 = (const float*)d_in[10];
  const float* bl1 = (const float*)d_in[11];
  const float* L2 = (const float*)d_in[12];
  const float* bl2 = (const float*)d_in[13];

  int N = in_sizes[0];
  int E = in_sizes[1] / 2;
  int EL = in_sizes[2] / 2;
  const int* src = ei;
  const int* dst = ei + E;

  int NB = (N + 1023) >> 10;            // 1024-node dst slices
  int qcap = E / NB + 4096;             // Poisson slack

  char* ws = (char*)d_ws;
  auto align256 = [](size_t v) { return (v + 255) & ~(size_t)255; };
  size_t p = 0;
  int* qcur = (int*)(ws + p); p += 4096;
  int* cnt = (int*)(ws + p); p += align256((size_t)N * 4);
  float* dinv = (float*)(ws + p); p += align256((size_t)N * 4);
  ushort* wfrag = (ushort*)(ws + p); p += align256(16384 * 2);
  float* wu = (float*)(ws + p); p += 512;
  float* wv = (float*)(ws + p); p += 512;
  float* cvals = (float*)(ws + p); p += 256;
  int* colsrc = (int*)(ws + p); p += align256((size_t)N * 64 * 4);
  unsigned* queues = (unsigned*)(ws + p); p += align256((size_t)NB * qcap * 4);
  unsigned* h1q = (unsigned*)(ws + p); p += align256((size_t)N * 64 * 4);
  int2* tuvi = (int2*)(ws + p); p += align256((size_t)N * 8);
  float* Su = (float*)(ws + p); p += align256((size_t)N * 4);
  float* Sv = (float*)(ws + p); p += align256((size_t)N * 4);
  (void)ws_size; (void)n_in; (void)out_size;

  prep<<<65, 256, 0, stream>>>(W1, W2, b2, L1, L2, bl1, bl2, wfrag, wu, wv,
                               cvals, qcur);
  bucket_edges<<<512, 256, 0, stream>>>(src, dst, E, NB, qcur, queues, qcap);
  scatter_ell<<<NB, 1024, 0, stream>>>(queues, qcur, qcap, cnt, dinv, colsrc, N);
  gemm1_mfma<<<(N + 127) / 128, 256, 0, stream>>>(x, emb, wfrag, dinv, h1q, N);
  agg1_ln<<<(N + 3) / 4, 256, 0, stream>>>(h1q, cnt, colsrc, dinv, b1, lng, lnb,
                                           wu, wv, tuvi, N);
  agg2<<<(N + 3) / 4, 256, 0, stream>>>(tuvi, cnt, colsrc, dinv, cvals, Su, Sv, N);
  decode<<<(EL + 255) / 256, 256, 0, stream>>>(eli, Su, Sv, cvals, (float*)d_out, EL);
}

// Round 19
// 163.596 us; speedup vs baseline: 1.4777x; 1.0265x over previous
//
#include <hip/hip_runtime.h>

// ---------------------------------------------------------------------------
// GCN link prediction forward on MI355X.  R19 = R17 numerics (int16 @2^11,
// int32 sums — absmax ~0.008, 4.5x margin; R18's packed-@2^7 was speed-null
// because agg1 is memory-bound) + 512-node dst slices (NB=196, 2x scatter
// parallelism).  Fixed-point sums are order-invariant -> bitwise
// deterministic regardless of atomic fill order.
//   h1i[n][d] = int16(round((emb[x]@W1)[d]*dinv[n]*2^11))
//   agg1: int32 sums -> LN(fp32 regs) -> tu/tv dots -> tuvi int2 @2^20
//   agg2: int32 sums of tuvi -> Su/Sv;  out[l] = Su[a]+Sv[b]+c0
// Linear collapse (R12): w=L1@L2, wu=W2@u, wv=W2@v; conv2+decode-MLP folded.
// agg1 gather is at the 8-XCD L2-replication floor: FETCH 190MB @ ~2.9TB/s
// (= per-XCD coupon-collector bound), confirmed by R7/R8/R10/R11/R18 probes.
// ---------------------------------------------------------------------------

typedef __attribute__((ext_vector_type(8))) __bf16 bf16x8;
typedef __attribute__((ext_vector_type(4))) float f32x4;

// blocks 0..63: W1 fragment table. block 64: linear-collapse constants + qcur=0.
__global__ __launch_bounds__(256) void prep(const float* __restrict__ W1,
                                            const float* __restrict__ W2,
                                            const float* __restrict__ b2,
                                            const float* __restrict__ L1,
                                            const float* __restrict__ L2,
                                            const float* __restrict__ bl1,
                                            const float* __restrict__ bl2,
                                            ushort* __restrict__ wfrag,
                                            float* __restrict__ wu,
                                            float* __restrict__ wv,
                                            float* __restrict__ cvals,
                                            int* __restrict__ qcur) {
  int t = threadIdx.x;
  if (blockIdx.x < 64) {
    int idx = blockIdx.x * 256 + t;  // 16384 elements
    int j = idx & 7, lane = (idx >> 3) & 63, ct = (idx >> 9) & 7, kt = idx >> 12;
    int k = kt * 32 + (lane >> 4) * 8 + j;
    int col = ct * 16 + (lane & 15);
    __bf16 h = (__bf16)W1[k * 128 + col];
    wfrag[idx] = __builtin_bit_cast(ushort, h);
    return;
  }
  for (int i = t; i < 1024; i += 256) qcur[i] = 0;
  __shared__ float us[32];  // w = L1@L2
  if (t < 32) {
    float a = 0.f;
    for (int j = 0; j < 16; ++j) a += L1[t * 16 + j] * L2[j];
    us[t] = a;
  }
  __syncthreads();
  if (t < 128) {
    float a = 0.f, b = 0.f;
    for (int k = 0; k < 16; ++k) {
      float w = W2[t * 16 + k];
      a += w * us[k];
      b += w * us[16 + k];
    }
    wu[t] = a;
    wv[t] = b;
  } else if (t == 128) {
    float a = 0.f;
    for (int k = 0; k < 16; ++k) a += b2[k] * us[k];
    cvals[0] = a;  // cu
  } else if (t == 129) {
    float a = 0.f;
    for (int k = 0; k < 16; ++k) a += b2[k] * us[16 + k];
    cvals[1] = a;  // cv
  } else if (t == 130) {
    float a = 0.f;
    for (int j = 0; j < 16; ++j) a += bl1[j] * L2[j];
    cvals[2] = a + bl2[0];  // c0
  }
}

// Pass 1: read edges once, route to NB per-slice queues (slice = 512 dsts).
// Entry = src | (localdst << 22)  (src < 2^22, localdst < 512).
__global__ __launch_bounds__(256) void bucket_edges(const int* __restrict__ src,
                                                    const int* __restrict__ dst,
                                                    int E, int NB,
                                                    int* __restrict__ qcur,
                                                    unsigned* __restrict__ queues,
                                                    int qcap) {
  __shared__ int lcnt[256];
  __shared__ int lbase[256];
  int t = threadIdx.x;
  int CH = (E + gridDim.x - 1) / gridDim.x;
  int beg = blockIdx.x * CH;
  int end = min(E, beg + CH);
  for (int i = t; i < NB; i += 256) lcnt[i] = 0;
  __syncthreads();
  for (int e = beg + t; e < end; e += 256) atomicAdd(&lcnt[dst[e] >> 9], 1);
  __syncthreads();
  for (int i = t; i < NB; i += 256) {
    lbase[i] = atomicAdd(&qcur[i], lcnt[i]);
    lcnt[i] = 0;
  }
  __syncthreads();
  for (int e = beg + t; e < end; e += 256) {  // chunk is L2-hot now
    int d = dst[e];
    int p = d >> 9;
    int pos = lbase[p] + atomicAdd(&lcnt[p], 1);
    if (pos < qcap)
      queues[(size_t)p * qcap + pos] =
          (unsigned)src[e] | ((unsigned)(d - (p << 9)) << 22);
  }
}

// Pass 2: one 512-thread block per 512-node slice; cnt in LDS; emits cnt+dinv.
// Fill order nondeterministic — harmless: downstream sums are integer.
__global__ __launch_bounds__(512) void scatter_ell(const unsigned* __restrict__ queues,
                                                   const int* __restrict__ qcur,
                                                   int qcap, int* __restrict__ cnt,
                                                   float* __restrict__ dinv,
                                                   int* __restrict__ colsrc, int N) {
  __shared__ int lcnt[512];
  int b = blockIdx.x, t = threadIdx.x;
  lcnt[t] = 0;
  __syncthreads();
  int len = min(qcur[b], qcap);
  const unsigned* q = queues + (size_t)b * qcap;
  int lo = b << 9;
  for (int i = t; i < len; i += 512) {
    unsigned u = q[i];
    unsigned ld = u >> 22;
    int pos = atomicAdd(&lcnt[ld], 1);
    if (pos < 64) colsrc[(size_t)(lo + ld) * 64 + pos] = (int)(u & 0x3FFFFFu);
  }
  __syncthreads();
  int node = lo + t;
  if (node < N) {
    int c = min(lcnt[t], 64);
    cnt[node] = c;
    dinv[node] = rsqrtf((float)(c + 1));
  }
}

// h1i[node][dim] int16 = round((emb[x[node]] @ W1) * dinv[node] * 2^11),
// via 16x16x32 MFMA. int16 @2^11 quantization is finer than bf16 here.
__global__ __launch_bounds__(256) void gemm1_mfma(
    const int* __restrict__ x, const float* __restrict__ emb,
    const ushort* __restrict__ wfrag, const float* __restrict__ dinv,
    unsigned* __restrict__ h1i, int N) {
  __shared__ alignas(16) ushort Wlds[16384];  // 32 KB frag table
  int t = threadIdx.x;
  for (int i = t; i < 2048; i += 256)
    ((uint4*)Wlds)[i] = ((const uint4*)wfrag)[i];
  __syncthreads();
  int w = t >> 6, lane = t & 63;
  int row0 = blockIdx.x * 128 + w * 32;  // this wave: nodes row0..row0+31
  int rB = lane & 15, kg = lane >> 4;
  int n0 = row0 + rB, n1 = row0 + 16 + rB;
  const float* e0 = emb + (size_t)x[min(n0, N - 1)] * 128 + kg * 8;
  const float* e1 = emb + (size_t)x[min(n1, N - 1)] * 128 + kg * 8;
  f32x4 acc[2][8];
#pragma unroll
  for (int g = 0; g < 2; ++g)
#pragma unroll
    for (int ct = 0; ct < 8; ++ct) acc[g][ct] = (f32x4)(0.f);
#pragma unroll
  for (int kt = 0; kt < 4; ++kt) {
    float4 p0 = *(const float4*)(e0 + kt * 32);
    float4 p1 = *(const float4*)(e0 + kt * 32 + 4);
    float4 q0 = *(const float4*)(e1 + kt * 32);
    float4 q1 = *(const float4*)(e1 + kt * 32 + 4);
    bf16x8 fb0, fb1;
    fb0[0] = (__bf16)p0.x; fb0[1] = (__bf16)p0.y; fb0[2] = (__bf16)p0.z; fb0[3] = (__bf16)p0.w;
    fb0[4] = (__bf16)p1.x; fb0[5] = (__bf16)p1.y; fb0[6] = (__bf16)p1.z; fb0[7] = (__bf16)p1.w;
    fb1[0] = (__bf16)q0.x; fb1[1] = (__bf16)q0.y; fb1[2] = (__bf16)q0.z; fb1[3] = (__bf16)q0.w;
    fb1[4] = (__bf16)q1.x; fb1[5] = (__bf16)q1.y; fb1[6] = (__bf16)q1.z; fb1[7] = (__bf16)q1.w;
#pragma unroll
    for (int ct = 0; ct < 8; ++ct) {
      bf16x8 wv = *(const bf16x8*)&Wlds[((kt * 8 + ct) * 64 + lane) * 8];
      acc[0][ct] = __builtin_amdgcn_mfma_f32_16x16x32_bf16(wv, fb0, acc[0][ct], 0, 0, 0);
      acc[1][ct] = __builtin_amdgcn_mfma_f32_16x16x32_bf16(wv, fb1, acc[1][ct], 0, 0, 0);
    }
  }
#pragma unroll
  for (int g = 0; g < 2; ++g) {
    int node = row0 + g * 16 + rB;
    if (node < N) {
      float dv2 = dinv[node] * 2048.f;
#pragma unroll
      for (int ct = 0; ct < 8; ++ct) {
        f32x4 a = acc[g][ct];
        int q0 = max(min((int)rintf(a[0] * dv2), 32767), -32767);
        int q1 = max(min((int)rintf(a[1] * dv2), 32767), -32767);
        int q2 = max(min((int)rintf(a[2] * dv2), 32767), -32767);
        int q3 = max(min((int)rintf(a[3] * dv2), 32767), -32767);
        uint2 o;
        o.x = ((unsigned)q0 & 0xFFFFu) | ((unsigned)q1 << 16);
        o.y = ((unsigned)q2 & 0xFFFFu) | ((unsigned)q3 << 16);
        *(uint2*)&h1i[(size_t)node * 64 + ct * 8 + kg * 2] = o;
      }
    }
  }
}

// wave/node: lane=(g,dq) g in [0,4), dq in [0,16); 16B/lane, 4-deep gather
// pipeline. int32 accumulation (order-invariant). Epilogue: LN in fp32,
// tu/tv dots vs wu/wv, write tuvi (int2 @2^20, clamp +-30).
__global__ __launch_bounds__(256) void agg1_ln(const unsigned* __restrict__ h1i,
                                               const int* __restrict__ cnt_a,
                                               const int* __restrict__ colsrc,
                                               const float* __restrict__ dinv,
                                               const float* __restrict__ b1,
                                               const float* __restrict__ lng,
                                               const float* __restrict__ lnb,
                                               const float* __restrict__ wu,
                                               const float* __restrict__ wv,
                                               int2* __restrict__ tuvi, int N) {
  int v = blockIdx.x * 4 + (threadIdx.x >> 6);
  int lane = threadIdx.x & 63;
  if (v >= N) return;
  int g = lane >> 4, dq = lane & 15;
  const uint4* tb = (const uint4*)h1i;  // row = 16 x uint4
  int cnt = cnt_a[v];
  int myidx = (lane < cnt) ? colsrc[(size_t)v * 64 + lane] : 0;
  int a0 = 0, a1 = 0, a2 = 0, a3 = 0, a4 = 0, a5 = 0, a6 = 0, a7 = 0;
#define ACC1(m)                                              \
  {                                                          \
    a0 += ((int)(m.x << 16)) >> 16; a1 += ((int)m.x) >> 16;  \
    a2 += ((int)(m.y << 16)) >> 16; a3 += ((int)m.y) >> 16;  \
    a4 += ((int)(m.z << 16)) >> 16; a5 += ((int)m.z) >> 16;  \
    a6 += ((int)(m.w << 16)) >> 16; a7 += ((int)m.w) >> 16;  \
  }
  if (g == 0) {  // self loop (pre-scaled)
    uint4 ms = tb[(size_t)v * 16 + dq];
    ACC1(ms);
  }
  int i = 0;
  for (; i + 16 <= cnt; i += 16) {  // 16 rows in flight across the wave
    int s0 = __shfl(myidx, i + g, 64);
    int s1_ = __shfl(myidx, i + 4 + g, 64);
    int s2_ = __shfl(myidx, i + 8 + g, 64);
    int s3_ = __shfl(myidx, i + 12 + g, 64);
    uint4 m0 = tb[(size_t)s0 * 16 + dq];
    uint4 m1 = tb[(size_t)s1_ * 16 + dq];
    uint4 m2 = tb[(size_t)s2_ * 16 + dq];
    uint4 m3 = tb[(size_t)s3_ * 16 + dq];
    ACC1(m0);
    ACC1(m1);
    ACC1(m2);
    ACC1(m3);
  }
  {  // tail: 4 predicated steps cover all <=15 remaining slots
    int slot0 = i + g, slot1 = i + 4 + g, slot2 = i + 8 + g, slot3 = i + 12 + g;
    int c1 = max(cnt - 1, 0);
    int t0 = __shfl(myidx, min(slot0, c1), 64);
    int t1 = __shfl(myidx, min(slot1, c1), 64);
    int t2 = __shfl(myidx, min(slot2, c1), 64);
    int t3 = __shfl(myidx, min(slot3, c1), 64);
    if (slot0 < cnt) { uint4 m = tb[(size_t)t0 * 16 + dq]; ACC1(m); }
    if (slot1 < cnt) { uint4 m = tb[(size_t)t1 * 16 + dq]; ACC1(m); }
    if (slot2 < cnt) { uint4 m = tb[(size_t)t2 * 16 + dq]; ACC1(m); }
    if (slot3 < cnt) { uint4 m = tb[(size_t)t3 * 16 + dq]; ACC1(m); }
  }
#undef ACC1
#pragma unroll
  for (int off = 16; off < 64; off <<= 1) {  // cross-group reduce (int, exact)
    a0 += __shfl_xor(a0, off, 64);
    a1 += __shfl_xor(a1, off, 64);
    a2 += __shfl_xor(a2, off, 64);
    a3 += __shfl_xor(a3, off, 64);
    a4 += __shfl_xor(a4, off, 64);
    a5 += __shfl_xor(a5, off, 64);
    a6 += __shfl_xor(a6, off, 64);
    a7 += __shfl_xor(a7, off, 64);
  }
  float dv = dinv[v];
  float dvq = dv * (1.f / 2048.f);
  float4 bb0 = ((const float4*)b1)[dq * 2];
  float4 bb1 = ((const float4*)b1)[dq * 2 + 1];
  float v0 = fmaxf((float)a0 * dvq + bb0.x, 0.f);
  float v1 = fmaxf((float)a1 * dvq + bb0.y, 0.f);
  float v2 = fmaxf((float)a2 * dvq + bb0.z, 0.f);
  float v3 = fmaxf((float)a3 * dvq + bb0.w, 0.f);
  float v4 = fmaxf((float)a4 * dvq + bb1.x, 0.f);
  float v5 = fmaxf((float)a5 * dvq + bb1.y, 0.f);
  float v6 = fmaxf((float)a6 * dvq + bb1.z, 0.f);
  float v7 = fmaxf((float)a7 * dvq + bb1.w, 0.f);
  float s1 = ((v0 + v1) + (v2 + v3)) + ((v4 + v5) + (v6 + v7));
  float s2 = ((v0 * v0 + v1 * v1) + (v2 * v2 + v3 * v3)) +
             ((v4 * v4 + v5 * v5) + (v6 * v6 + v7 * v7));
#pragma unroll
  for (int off = 1; off < 16; off <<= 1) {  // LN reduce within 16-lane group
    s1 += __shfl_xor(s1, off, 64);
    s2 += __shfl_xor(s2, off, 64);
  }
  float mu = s1 * (1.f / 128.f);
  float var = s2 * (1.f / 128.f) - mu * mu;
  float rs = rsqrtf(var + 1e-5f);
  float4 gg0 = ((const float4*)lng)[dq * 2];
  float4 gg1 = ((const float4*)lng)[dq * 2 + 1];
  float4 nb0 = ((const float4*)lnb)[dq * 2];
  float4 nb1 = ((const float4*)lnb)[dq * 2 + 1];
  float h0 = (v0 - mu) * rs * gg0.x + nb0.x;
  float h1 = (v1 - mu) * rs * gg0.y + nb0.y;
  float h2_ = (v2 - mu) * rs * gg0.z + nb0.z;
  float h3 = (v3 - mu) * rs * gg0.w + nb0.w;
  float h4 = (v4 - mu) * rs * gg1.x + nb1.x;
  float h5 = (v5 - mu) * rs * gg1.y + nb1.y;
  float h6 = (v6 - mu) * rs * gg1.z + nb1.z;
  float h7 = (v7 - mu) * rs * gg1.w + nb1.w;
  float4 ua = ((const float4*)wu)[dq * 2], ub = ((const float4*)wu)[dq * 2 + 1];
  float4 va = ((const float4*)wv)[dq * 2], vb = ((const float4*)wv)[dq * 2 + 1];
  float pu = ((h0 * ua.x + h1 * ua.y) + (h2_ * ua.z + h3 * ua.w)) +
             ((h4 * ub.x + h5 * ub.y) + (h6 * ub.z + h7 * ub.w));
  float pv = ((h0 * va.x + h1 * va.y) + (h2_ * va.z + h3 * va.w)) +
             ((h4 * vb.x + h5 * vb.y) + (h6 * vb.z + h7 * vb.w));
#pragma unroll
  for (int off = 1; off < 16; off <<= 1) {  // reduce over dq within group
    pu += __shfl_xor(pu, off, 64);
    pv += __shfl_xor(pv, off, 64);
  }
  if (lane == 0) {
    float tu_ = fminf(fmaxf(pu * dv, -30.f), 30.f);
    float tv_ = fminf(fmaxf(pv * dv, -30.f), 30.f);
    int2 o;
    o.x = (int)rintf(tu_ * 1048576.f);
    o.y = (int)rintf(tv_ * 1048576.f);
    tuvi[v] = o;
  }
}

// wave/node: 32 groups x 2 lanes; 8B int2 gather from L2-resident tuvi.
// Integer sums -> order-invariant -> deterministic.
__global__ __launch_bounds__(256) void agg2(const int2* __restrict__ tuvi,
                                            const int* __restrict__ cnt_a,
                                            const int* __restrict__ colsrc,
                                            const float* __restrict__ dinv,
                                            const float* __restrict__ cvals,
                                            float* __restrict__ Su,
                                            float* __restrict__ Sv, int N) {
  int v = blockIdx.x * 4 + (threadIdx.x >> 6);
  int lane = threadIdx.x & 63;
  if (v >= N) return;
  int g = lane >> 1, q = lane & 1;
  int cnt = cnt_a[v];
  int myidx = (lane < cnt) ? colsrc[(size_t)v * 64 + lane] : 0;
  int acc = 0;
  if (g == 0) {  // self loop
    int2 ts = tuvi[v];
    acc = q ? ts.y : ts.x;
  }
  for (int i = 0; i < cnt; i += 32) {
    int slot = i + g;
    int s = __shfl(myidx, max(min(slot, cnt - 1), 0), 64);
    int2 m = tuvi[s];
    if (slot < cnt) acc += q ? m.y : m.x;
  }
#pragma unroll
  for (int off = 2; off < 64; off <<= 1) acc += __shfl_xor(acc, off, 64);
  if (lane < 2) {
    float r = (float)acc * (1.f / 1048576.f) * dinv[v] + cvals[q];
    if (q == 0) Su[v] = r;
    else Sv[v] = r;
  }
}

__global__ __launch_bounds__(256) void decode(const int* __restrict__ eli,
                                              const float* __restrict__ Su,
                                              const float* __restrict__ Sv,
                                              const float* __restrict__ cvals,
                                              float* __restrict__ out, int EL) {
  int l = blockIdx.x * 256 + threadIdx.x;
  if (l >= EL) return;
  out[l] = Su[eli[l]] + Sv[eli[EL + l]] + cvals[2];
}

extern "C" void kernel_launch(void* const* d_in, const int* in_sizes, int n_in,
                              void* d_out, int out_size, void* d_ws, size_t ws_size,
                              hipStream_t stream) {
  const int* x = (const int*)d_in[0];
  const int* ei = (const int*)d_in[1];
  const int* eli = (const int*)d_in[2];
  const float* emb = (const float*)d_in[3];
  const float* W1 = (const float*)d_in[4];
  const float* b1 = (const float*)d_in[5];
  const float* lng = (const float*)d_in[6];
  const float* lnb = (const float*)d_in[7];
  const float* W2 = (const float*)d_in[8];
  const float* b2 = (const float*)d_in[9];
  const float* L1 = (const float*)d_in[10];
  const float* bl1 = (const float*)d_in[11];
  const float* L2 = (const float*)d_in[12];
  const float* bl2 = (const float*)d_in[13];

  int N = in_sizes[0];
  int E = in_sizes[1] / 2;
  int EL = in_sizes[2] / 2;
  const int* src = ei;
  const int* dst = ei + E;

  int NB = (N + 511) >> 9;              // 512-node dst slices (196 for N=100k)
  int qcap = E / NB + 3072;             // Poisson slack (~8.2k + 3k)

  char* ws = (char*)d_ws;
  auto align256 = [](size_t v) { return (v + 255) & ~(size_t)255; };
  size_t p = 0;
  int* qcur = (int*)(ws + p); p += 4096;
  int* cnt = (int*)(ws + p); p += align256((size_t)N * 4);
  float* dinv = (float*)(ws + p); p += align256((size_t)N * 4);
  ushort* wfrag = (ushort*)(ws + p); p += align256(16384 * 2);
  float* wu = (float*)(ws + p); p += 512;
  float* wv = (float*)(ws + p); p += 512;
  float* cvals = (float*)(ws + p); p += 256;
  int* colsrc = (int*)(ws + p); p += align256((size_t)N * 64 * 4);
  unsigned* queues = (unsigned*)(ws + p); p += align256((size_t)NB * qcap * 4);
  unsigned* h1i = (unsigned*)(ws + p); p += align256((size_t)N * 64 * 4);
  int2* tuvi = (int2*)(ws + p); p += align256((size_t)N * 8);
  float* Su = (float*)(ws + p); p += align256((size_t)N * 4);
  float* Sv = (float*)(ws + p); p += align256((size_t)N * 4);
  (void)ws_size; (void)n_in; (void)out_size;

  prep<<<65, 256, 0, stream>>>(W1, W2, b2, L1, L2, bl1, bl2, wfrag, wu, wv,
                               cvals, qcur);
  bucket_edges<<<512, 256, 0, stream>>>(src, dst, E, NB, qcur, queues, qcap);
  scatter_ell<<<NB, 512, 0, stream>>>(queues, qcur, qcap, cnt, dinv, colsrc, N);
  gemm1_mfma<<<(N + 127) / 128, 256, 0, stream>>>(x, emb, wfrag, dinv, h1i, N);
  agg1_ln<<<(N + 3) / 4, 256, 0, stream>>>(h1i, cnt, colsrc, dinv, b1, lng, lnb,
                                           wu, wv, tuvi, N);
  agg2<<<(N + 3) / 4, 256, 0, stream>>>(tuvi, cnt, colsrc, dinv, cvals, Su, Sv, N);
  decode<<<(EL + 255) / 256, 256, 0, stream>>>(eli, Su, Sv, cvals, (float*)d_out, EL);
}